// Round 1
// baseline (39001.648 us; speedup 1.0000x reference)
//
#include <hip/hip_runtime.h>
#include <cmath>

// ---- problem constants ----
#define BB 8
#define MMq 512           // query block length
#define SSp 1024          // attention span / cache len
#define HH 768
#define KH 12             // heads
#define DD 64             // head dim
#define NLAYER 4
#define FFN 3072
#define VV 32000
#define NTOK (BB*MMq)     // 4096 rows of h
#define SM (SSp+MMq)      // 1536
#define NALL (BB*SM)      // 12288 rows of h_all

// ================= block reduction helpers (blockDim.x == 256) =================
__device__ __forceinline__ float block_sum256(float v, float* red4) {
#pragma unroll
    for (int off = 32; off > 0; off >>= 1) v += __shfl_down(v, off);
    int lane = threadIdx.x & 63, w = threadIdx.x >> 6;
    if (lane == 0) red4[w] = v;
    __syncthreads();
    float r = red4[0] + red4[1] + red4[2] + red4[3];
    __syncthreads();
    return r;
}

__device__ __forceinline__ float block_max256(float v, float* red4) {
#pragma unroll
    for (int off = 32; off > 0; off >>= 1) v = fmaxf(v, __shfl_down(v, off));
    int lane = threadIdx.x & 63, w = threadIdx.x >> 6;
    if (lane == 0) red4[w] = v;
    __syncthreads();
    float r = fmaxf(fmaxf(red4[0], red4[1]), fmaxf(red4[2], red4[3]));
    __syncthreads();
    return r;
}

// ================= embedding gather: h[row,:] = emb[x[row],:] =================
__global__ __launch_bounds__(256) void embed_kernel(
    const int* __restrict__ x, const float* __restrict__ emb, float* __restrict__ h)
{
    int row = blockIdx.x;                 // 0..NTOK-1
    int token = x[row];
    const float* e = emb + (size_t)token * HH;
    float* o = h + (size_t)row * HH;
    for (int c = threadIdx.x; c < HH; c += 256) o[c] = e[c];
}

// ================= concat: h_all = [cache_l ; h] per batch =================
__global__ __launch_bounds__(256) void concat_kernel(
    const float* __restrict__ cache,   // [BB, SSp, HH] (layer slice)
    const float* __restrict__ h,       // [BB, MMq, HH]
    float* __restrict__ h_all)         // [BB, SM, HH]
{
    size_t idx = (size_t)blockIdx.x * 256 + threadIdx.x;
    if (idx >= (size_t)NALL * HH) return;
    int c = (int)(idx % HH);
    size_t t = idx / HH;
    int pos = (int)(t % SM);
    int b = (int)(t / SM);
    float v;
    if (pos < SSp) v = cache[((size_t)b * SSp + pos) * HH + c];
    else           v = h[((size_t)b * MMq + (pos - SSp)) * HH + c];
    h_all[idx] = v;
}

// ================= generic tiled fp32 GEMM: C = A@W (+bias) (+relu) =================
// A: [Nrows, Kd] row-major, W: [Kd, Nc] row-major, C: [Nrows, Nc]
// Requires Nrows%64==0, Nc%64==0, Kd%16==0 (true for all shapes here).
#define GBM 64
#define GBN 64
#define GBK 16
__global__ __launch_bounds__(256) void gemm_kernel(
    const float* __restrict__ A, const float* __restrict__ W,
    const float* __restrict__ bias, float* __restrict__ C,
    int Nrows, int Kd, int Nc, int relu)
{
    __shared__ float As[GBK][GBM + 1];   // [k][m], +1 pad: conflict-free stores
    __shared__ float Bs[GBK][GBN + 1];   // [k][n]
    int tid = threadIdx.x;
    int bm = blockIdx.y * GBM;
    int bn = blockIdx.x * GBN;
    int tx = tid & 15, ty = tid >> 4;    // 16x16 threads, 4x4 microtile each
    float acc[4][4] = {{0.f}};

    for (int k0 = 0; k0 < Kd; k0 += GBK) {
        __syncthreads();
        {
            int ca = tid & 15, ra = tid >> 4;          // A: col-in-tile, row base
#pragma unroll
            for (int ii = 0; ii < 4; ++ii) {
                int m = ra + 16 * ii;
                As[ca][m] = A[(size_t)(bm + m) * Kd + (k0 + ca)];
            }
            int cb = tid & 63, rb = tid >> 6;          // W loader
#pragma unroll
            for (int ii = 0; ii < 4; ++ii) {
                int kk = rb + 4 * ii;
                Bs[kk][cb] = W[(size_t)(k0 + kk) * Nc + (bn + cb)];
            }
        }
        __syncthreads();
#pragma unroll
        for (int kk = 0; kk < GBK; ++kk) {
            float a[4], bv[4];
#pragma unroll
            for (int i = 0; i < 4; ++i) a[i] = As[kk][ty * 4 + i];
#pragma unroll
            for (int j = 0; j < 4; ++j) bv[j] = Bs[kk][tx * 4 + j];
#pragma unroll
            for (int i = 0; i < 4; ++i)
#pragma unroll
                for (int j = 0; j < 4; ++j)
                    acc[i][j] += a[i] * bv[j];
        }
    }
#pragma unroll
    for (int i = 0; i < 4; ++i) {
        int row = bm + ty * 4 + i;
#pragma unroll
        for (int j = 0; j < 4; ++j) {
            int col = bn + tx * 4 + j;
            float v = acc[i][j];
            if (bias) v += bias[col];
            if (relu) v = fmaxf(v, 0.f);
            C[(size_t)row * Nc + col] = v;
        }
    }
}

// ================= fused sliding-window attention =================
// grid: (MMq, BB*KH), block 256. One block = one (head, query) pair.
// scores[j] = (q_i . k_{i+j}  +  q_i . pe[:,j]) / 8 ; softmax over j in [0,1024)
// ctx[d] = sum_j p_j * v[i+j, d]
__global__ __launch_bounds__(256) void attn_kernel(
    const float* __restrict__ q,      // [BB, MMq, HH]
    const float* __restrict__ kbuf,   // [BB, SM, HH]
    const float* __restrict__ vbuf,   // [BB, SM, HH]
    const float* __restrict__ pe,     // [DD, SSp]
    float* __restrict__ ctx)          // [BB, MMq, HH]
{
    int i = blockIdx.x;               // query index
    int bk = blockIdx.y;              // b*KH + head
    int b = bk / KH, hh = bk % KH;
    int tid = threadIdx.x;

    __shared__ float sq[DD];
    __shared__ float sc[SSp];
    __shared__ float red4[4];
    __shared__ float part[4][DD];

    const float* qrow = q + ((size_t)(b * MMq + i) * HH) + hh * DD;
    if (tid < DD) sq[tid] = qrow[tid];
    __syncthreads();

    const float* kb = kbuf + (size_t)b * SM * HH + hh * DD;
#pragma unroll
    for (int jj = 0; jj < 4; ++jj) {
        int j = tid + jj * 256;
        const float* krow = kb + (size_t)(i + j) * HH;
        float s = 0.f;
#pragma unroll
        for (int d = 0; d < DD; ++d) s += sq[d] * krow[d];
        float p = 0.f;
#pragma unroll
        for (int d = 0; d < DD; ++d) p += sq[d] * pe[d * SSp + j];
        sc[j] = (s + p) * 0.125f;     // 1/sqrt(64)
    }
    __syncthreads();

    float lm = -INFINITY;
#pragma unroll
    for (int jj = 0; jj < 4; ++jj) lm = fmaxf(lm, sc[tid + jj * 256]);
    float mx = block_max256(lm, red4);

    float lsum = 0.f;
#pragma unroll
    for (int jj = 0; jj < 4; ++jj) {
        int j = tid + jj * 256;
        float e = __expf(sc[j] - mx);
        sc[j] = e;
        lsum += e;
    }
    float ssum = block_sum256(lsum, red4);   // internal syncthreads makes sc visible
    float inv = 1.f / ssum;

    int d = tid & 63, c = tid >> 6;
    const float* vb = vbuf + (size_t)b * SM * HH + hh * DD + d;
    float accv = 0.f;
    int j0 = c * 256;
    for (int j = j0; j < j0 + 256; ++j) accv += sc[j] * vb[(size_t)(i + j) * HH];
    part[c][d] = accv;
    __syncthreads();
    if (tid < DD) {
        float o = (part[0][tid] + part[1][tid] + part[2][tid] + part[3][tid]) * inv;
        ctx[((size_t)(b * MMq + i) * HH) + hh * DD + tid] = o;
    }
}

// ================= LayerNorm(x + add) * s + b =================
__global__ __launch_bounds__(256) void ln_kernel(
    const float* __restrict__ x, const float* __restrict__ addv,
    const float* __restrict__ s, const float* __restrict__ bparam,
    float* __restrict__ out)
{
    __shared__ float red4[4];
    int row = blockIdx.x;
    const float* xr = x + (size_t)row * HH;
    const float* ar = addv + (size_t)row * HH;
    float vals[3];                       // 768 / 256 == 3
    float lsum = 0.f;
    int idx = 0;
    for (int c = threadIdx.x; c < HH; c += 256, ++idx) {
        float v = xr[c] + ar[c];
        vals[idx] = v;
        lsum += v;
    }
    float mu = block_sum256(lsum, red4) * (1.f / HH);
    float lvar = 0.f;
#pragma unroll
    for (int k = 0; k < 3; ++k) { float dv = vals[k] - mu; lvar += dv * dv; }
    float var = block_sum256(lvar, red4) * (1.f / HH);
    float rinv = rsqrtf(var + 1e-5f);
    float* orow = out + (size_t)row * HH;
    idx = 0;
    for (int c = threadIdx.x; c < HH; c += 256, ++idx)
        orow[c] = (vals[idx] - mu) * rinv * s[c] + bparam[c];
}

// ================= in-place log_softmax over last dim V =================
__global__ __launch_bounds__(256) void logsoftmax_kernel(float* __restrict__ logits)
{
    __shared__ float red4[4];
    int row = blockIdx.x;
    float* p = logits + (size_t)row * VV;
    float lm = -INFINITY;
    for (int c = threadIdx.x; c < VV; c += 256) lm = fmaxf(lm, p[c]);
    float mx = block_max256(lm, red4);
    float lsum = 0.f;
    for (int c = threadIdx.x; c < VV; c += 256) lsum += __expf(p[c] - mx);
    float ssum = block_sum256(lsum, red4);
    float lse = mx + logf(ssum);
    for (int c = threadIdx.x; c < VV; c += 256) p[c] = p[c] - lse;
}

// ================= orchestration =================
static inline void launch_gemm(const float* A, const float* W, const float* bias,
                               float* C, int Nrows, int Kd, int Nc, int relu,
                               hipStream_t stream)
{
    dim3 grid(Nc / GBN, Nrows / GBM);
    gemm_kernel<<<grid, 256, 0, stream>>>(A, W, bias, C, Nrows, Kd, Nc, relu);
}

extern "C" void kernel_launch(void* const* d_in, const int* in_sizes, int n_in,
                              void* d_out, int out_size, void* d_ws, size_t ws_size,
                              hipStream_t stream)
{
    const int*   x       = (const int*)d_in[0];
    const float* h_cache = (const float*)d_in[1];   // [NL, BB, SSp, HH]
    const float* key_pe  = (const float*)d_in[2];   // [1, DD, SSp]
    const float* emb     = (const float*)d_in[3];   // [VV, HH]
    const float* Wq      = (const float*)d_in[4];   // [NL, HH, HH]
    const float* Wk      = (const float*)d_in[5];
    const float* Wv      = (const float*)d_in[6];
    const float* Wo      = (const float*)d_in[7];
    const float* fc1_w   = (const float*)d_in[8];   // [NL, HH, FFN]
    const float* fc1_b   = (const float*)d_in[9];   // [NL, FFN]
    const float* fc2_w   = (const float*)d_in[10];  // [NL, FFN, HH]
    const float* fc2_b   = (const float*)d_in[11];  // [NL, HH]
    const float* ln1_s   = (const float*)d_in[12];
    const float* ln1_b   = (const float*)d_in[13];
    const float* ln2_s   = (const float*)d_in[14];
    const float* ln2_b   = (const float*)d_in[15];
    const float* out_w   = (const float*)d_in[16];  // [HH, VV]
    const float* out_b   = (const float*)d_in[17];  // [VV]
    float* out = (float*)d_out;

    // workspace layout (floats)
    float* ws = (float*)d_ws;
    size_t off = 0;
    float* hA    = ws + off; off += (size_t)NTOK * HH;
    float* hB    = ws + off; off += (size_t)NTOK * HH;
    float* h_all = ws + off; off += (size_t)NALL * HH;
    float* qb    = ws + off; off += (size_t)NTOK * HH;   // also reused as Wo-proj out
    float* kb    = ws + off; off += (size_t)NALL * HH;
    float* vb    = ws + off; off += (size_t)NALL * HH;
    float* ctx   = ws + off; off += (size_t)NTOK * HH;   // attn out, also fc2 out
    float* ff    = ws + off; off += (size_t)NTOK * FFN;
    if (ws_size < off * sizeof(float)) return;           // workspace too small: bail

    embed_kernel<<<NTOK, 256, 0, stream>>>(x, emb, hA);

    for (int l = 0; l < NLAYER; ++l) {
        const float* cache_l = h_cache + (size_t)l * BB * SSp * HH;
        {
            size_t total = (size_t)NALL * HH;
            int blocks = (int)((total + 255) / 256);
            concat_kernel<<<blocks, 256, 0, stream>>>(cache_l, hA, h_all);
        }
        launch_gemm(hA,    Wq + (size_t)l * HH * HH, nullptr, qb, NTOK, HH, HH, 0, stream);
        launch_gemm(h_all, Wk + (size_t)l * HH * HH, nullptr, kb, NALL, HH, HH, 0, stream);
        launch_gemm(h_all, Wv + (size_t)l * HH * HH, nullptr, vb, NALL, HH, HH, 0, stream);

        attn_kernel<<<dim3(MMq, BB * KH), 256, 0, stream>>>(qb, kb, vb, key_pe, ctx);

        // o-proj into qb (q no longer needed), then h_mid = LN1(hA + qb)
        launch_gemm(ctx, Wo + (size_t)l * HH * HH, nullptr, qb, NTOK, HH, HH, 0, stream);
        ln_kernel<<<NTOK, 256, 0, stream>>>(hA, qb, ln1_s + (size_t)l * HH,
                                            ln1_b + (size_t)l * HH, hB);

        // FFN: ff = relu(hB @ fc1 + b1); ctx = ff @ fc2 + b2 ; hA = LN2(hB + ctx)
        launch_gemm(hB, fc1_w + (size_t)l * HH * FFN, fc1_b + (size_t)l * FFN,
                    ff, NTOK, HH, FFN, 1, stream);
        launch_gemm(ff, fc2_w + (size_t)l * FFN * HH, fc2_b + (size_t)l * HH,
                    ctx, NTOK, FFN, HH, 0, stream);
        ln_kernel<<<NTOK, 256, 0, stream>>>(hB, ctx, ln2_s + (size_t)l * HH,
                                            ln2_b + (size_t)l * HH, hA);
    }

    // final projection into d_out, then in-place log_softmax
    launch_gemm(hA, out_w, out_b, out, NTOK, HH, VV, 0, stream);
    logsoftmax_kernel<<<NTOK, 256, 0, stream>>>(out);
}